// Round 7
// baseline (1995.406 us; speedup 1.0000x reference)
//
#include <hip/hip_runtime.h>

#define CHUNK 400
#define LWIN 50
#define JUMP 8
#define NCH 128
#define BCH 128
#define HCH 512
#define NBLK 14
#define BUF 516
#define SHIFT 508
#define EPSV 1e-8f
#define NWG 65
#define FR 8

__device__ __forceinline__ void gsync(unsigned* bar, int slot, int tid) {
    __syncthreads();                       // drains vmcnt: all WG writes at L2
    if (tid == 0) {
        unsigned* p = bar + slot;
        __hip_atomic_fetch_add(p, 1u, __ATOMIC_RELEASE, __HIP_MEMORY_SCOPE_AGENT);
        while (__hip_atomic_load(p, __ATOMIC_RELAXED, __HIP_MEMORY_SCOPE_AGENT) < NWG)
            __builtin_amdgcn_s_sleep(8);
        (void)__hip_atomic_load(p, __ATOMIC_ACQUIRE, __HIP_MEMORY_SCOPE_AGENT);
    }
    __syncthreads();
}

// stage1: yout[t0..t0+nf) = cLN(PReLU(w1row @ xs)); weights read from L2
__device__ __forceinline__ void stage1_core(
    int tid, int lane, int wid, int t0, int nf,
    const float* __restrict__ w1b, float aPr,
    const float* __restrict__ gv, const float* __restrict__ bv,
    float* __restrict__ yout, float* redf, float* statsf, const float* xsv)
{
    const float4* __restrict__ wr = (const float4*)(w1b + (size_t)tid * BCH);
    const float4* __restrict__ xv = (const float4*)xsv;
    float acc[FR] = {};
    #pragma unroll
    for (int c4 = 0; c4 < 32; ++c4) {
        float4 w = wr[c4];
        #pragma unroll
        for (int f = 0; f < FR; ++f) {
            float4 x = xv[f * 32 + c4];
            acc[f] += w.x * x.x + w.y * x.y + w.z * x.z + w.w * x.w;
        }
    }
    #pragma unroll
    for (int f = 0; f < FR; ++f) acc[f] = acc[f] >= 0.f ? acc[f] : aPr * acc[f];
    #pragma unroll
    for (int f = 0; f < FR; ++f) {
        if (f < nf) {
            float s = acc[f], q = acc[f] * acc[f];
            #pragma unroll
            for (int o = 32; o; o >>= 1) { s += __shfl_xor(s, o); q += __shfl_xor(q, o); }
            if (lane == 0) { redf[(wid * FR + f) * 2] = s; redf[(wid * FR + f) * 2 + 1] = q; }
        }
    }
    __syncthreads();
    if (tid < nf) {
        float s = 0.f, q = 0.f;
        #pragma unroll
        for (int w = 0; w < 8; ++w) { s += redf[(w * FR + tid) * 2]; q += redf[(w * FR + tid) * 2 + 1]; }
        float mean = s * (1.f / HCH);
        float var = q * (1.f / HCH) - mean * mean;
        statsf[tid * 2] = mean; statsf[tid * 2 + 1] = rsqrtf(var + EPSV);
    }
    __syncthreads();
    float gg = gv[tid], bb = bv[tid];
    #pragma unroll
    for (int f = 0; f < FR; ++f)
        if (f < nf)
            yout[(t0 + f) * HCH + tid] = gg * (acc[f] - statsf[f * 2]) * statsf[f * 2 + 1] + bb;
}

__global__ __launch_bounds__(512, 1) void k_fused(
    const float* __restrict__ mixture, const float* __restrict__ inEnc,
    const float* __restrict__ inLn, const float* __restrict__ Wenc,
    const float* __restrict__ lng, const float* __restrict__ lnb,
    const float* __restrict__ Wbn, const float* __restrict__ w1,
    const float* __restrict__ p1, const float* __restrict__ g1,
    const float* __restrict__ b1, const float* __restrict__ dwc,
    const float* __restrict__ p2, const float* __restrict__ g2,
    const float* __restrict__ b2, const float* __restrict__ w2,
    const float* __restrict__ Wmask, const float* __restrict__ Wdec,
    float* __restrict__ est, float* __restrict__ outEnc, float* __restrict__ outLn,
    unsigned* __restrict__ bar,
    float* __restrict__ xA, float* __restrict__ xB,
    float* __restrict__ y1nA, float* __restrict__ y1nB)
{
    __shared__ float xs[FR * BCH];      // stage1 input frames / final-x for mask
    __shared__ float ys[FR * 528];      // stage2 normalized; front scratch; mask sw
    __shared__ float encs[FR * NCH];    // WG0 front scratch
    __shared__ float redf[8 * FR * 2];
    __shared__ float statsf[FR * 2];

    const int wg = blockIdx.x;
    const int tid = threadIdx.x;
    const int lane = tid & 63, wid = tid >> 6;
    const int c = tid >> 2, p = tid & 3;

    // ================= Phase F: front (WG0) | buffer copies (WGs 1..64) ======
    if (wg == 0) {
        #pragma unroll
        for (int k = 0; k < 2; ++k) {
            int o = tid + k * 512;
            int cc = o >> 3, f = o & 7;
            const float* w = Wenc + cc * 100;
            const float* m = mixture + f * LWIN;
            float e = 0.f;
            #pragma unroll 10
            for (int l = 0; l < LWIN; ++l) e += m[l] * w[l] + m[CHUNK + l] * w[LWIN + l];
            e = fmaxf(e, 0.f);
            encs[f * NCH + cc] = e;
            outEnc[cc * BUF + SHIFT + f] = e;
        }
        __syncthreads();
        {   // cLN over channels: wave wid handles frame wid
            float v0 = encs[wid * NCH + lane], v1 = encs[wid * NCH + 64 + lane];
            float s = v0 + v1, q = v0 * v0 + v1 * v1;
            #pragma unroll
            for (int o = 32; o; o >>= 1) { s += __shfl_xor(s, o); q += __shfl_xor(q, o); }
            float mean = s * (1.f / NCH);
            float var = q * (1.f / NCH) - mean * mean;
            float r = rsqrtf(var + EPSV);
            ys[wid * NCH + lane] = lng[lane] * (v0 - mean) * r + lnb[lane];
            ys[wid * NCH + 64 + lane] = lng[64 + lane] * (v1 - mean) * r + lnb[64 + lane];
        }
        __syncthreads();
        #pragma unroll
        for (int k = 0; k < 2; ++k) {   // bottleneck 1x1
            int o = tid + k * 512;
            int b = o & 127, f = o >> 7;
            float acc = 0.f;
            const float4* wr = (const float4*)(Wbn + b * NCH);
            const float4* nv = (const float4*)(ys + f * NCH);
            #pragma unroll
            for (int j4 = 0; j4 < 32; ++j4) {
                float4 w = wr[j4]; float4 x = nv[j4];
                acc += w.x * x.x + w.y * x.y + w.z * x.z + w.w * x.w;
            }
            outLn[b * BUF + SHIFT + f] = acc;
            xA[(SHIFT + f) * BCH + b] = acc;
        }
    } else {
        int c0 = (wg - 1) * 2;
        #pragma unroll
        for (int cc = 0; cc < 2; ++cc) {
            int ch = c0 + cc;
            if (tid < SHIFT) {
                outEnc[ch * BUF + tid] = inEnc[ch * BUF + tid + JUMP];
                float v = inLn[ch * BUF + tid + JUMP];
                outLn[ch * BUF + tid] = v;
                xA[tid * BCH + ch] = v;
            }
        }
    }
    gsync(bar, 0, tid);

    // ================= stage1 of block 0 =====================================
    int T = BUF;
    {
        int FPW = (T + NWG - 1) / NWG;          // 8
        int t0 = wg * FPW;
        if (t0 < T) {
            int nf = min(FPW, T - t0);
            #pragma unroll
            for (int k = 0; k < 2; ++k) {
                int o = tid + k * 512;
                xs[o] = (o < nf * BCH) ? xA[t0 * BCH + o] : 0.f;
            }
            __syncthreads();
            stage1_core(tid, lane, wid, t0, nf, w1, p1[0], g1, b1, y1nA, redf, statsf, xs);
        }
    }
    gsync(bar, 1, tid);

    // ================= fused stage2(i) + stage1(i+1) =========================
    const float* xin = xA;  float* xout = xB;
    const float* ycur = y1nA; float* ynext = y1nB;
    for (int i = 0; i < NBLK; ++i) {
        int d = 1 << (i % 7);
        int Tout = T - 2 * d;
        int FPW = (Tout + NWG - 1) / NWG;
        int t0 = wg * FPW;
        bool act = t0 < Tout;           // WG-uniform; may toggle across i (FPW shrinks)
        int nf = act ? min(FPW, Tout - t0) : 0;
        if (act) {
            const float* dwb = dwc + (size_t)i * HCH * 3 + tid * 3;
            float dw0 = dwb[0], dw1 = dwb[1], dw2 = dwb[2];
            float a2 = p2[i];
            float resv[FR];
            #pragma unroll
            for (int f = 0; f < FR; ++f)
                resv[f] = (f < nf && p == 0) ? xin[(t0 + f + 2 * d) * BCH + c] : 0.f;
            // ---- depthwise conv + PReLU ----
            float yv[FR];
            #pragma unroll
            for (int f = 0; f < FR; ++f) {
                if (f < nf) {
                    int t = t0 + f;
                    float v = dw0 * ycur[t * HCH + tid] + dw1 * ycur[(t + d) * HCH + tid]
                            + dw2 * ycur[(t + 2 * d) * HCH + tid];
                    yv[f] = v >= 0.f ? v : a2 * v;
                } else yv[f] = 0.f;
            }
            // ---- cLN over H ----
            #pragma unroll
            for (int f = 0; f < FR; ++f) {
                if (f < nf) {
                    float s = yv[f], q = yv[f] * yv[f];
                    #pragma unroll
                    for (int o = 32; o; o >>= 1) { s += __shfl_xor(s, o); q += __shfl_xor(q, o); }
                    if (lane == 0) { redf[(wid * FR + f) * 2] = s; redf[(wid * FR + f) * 2 + 1] = q; }
                }
            }
            __syncthreads();
            if (tid < nf) {
                float s = 0.f, q = 0.f;
                #pragma unroll
                for (int w = 0; w < 8; ++w) { s += redf[(w * FR + tid) * 2]; q += redf[(w * FR + tid) * 2 + 1]; }
                float mean = s * (1.f / HCH);
                float var = q * (1.f / HCH) - mean * mean;
                statsf[tid * 2] = mean; statsf[tid * 2 + 1] = rsqrtf(var + EPSV);
            }
            __syncthreads();
            {
                float gg = g2[i * HCH + tid], bb = b2[i * HCH + tid];
                int pidx = (tid >> 7) * 132 + (tid & 127);
                #pragma unroll
                for (int f = 0; f < FR; ++f)
                    if (f < nf)
                        ys[f * 528 + pidx] = gg * (yv[f] - statsf[f * 2]) * statsf[f * 2 + 1] + bb;
            }
            __syncthreads();
            // ---- w2 GEMM (K split by 4, weights streamed from L2) ----
            float acc2[FR] = {};
            const float4* __restrict__ wr2 =
                (const float4*)(w2 + (size_t)i * BCH * HCH + (size_t)c * HCH + p * 128);
            #pragma unroll
            for (int j4 = 0; j4 < 32; ++j4) {
                float4 w = wr2[j4];
                #pragma unroll
                for (int f = 0; f < FR; ++f) {
                    float4 x = *(const float4*)&ys[f * 528 + p * 132 + j4 * 4];
                    acc2[f] += w.x * x.x + w.y * x.y + w.z * x.z + w.w * x.w;
                }
            }
            #pragma unroll
            for (int f = 0; f < FR; ++f) {
                acc2[f] += __shfl_xor(acc2[f], 1);
                acc2[f] += __shfl_xor(acc2[f], 2);
            }
            if (p == 0) {
                #pragma unroll
                for (int f = 0; f < FR; ++f) {
                    if (f < nf) {
                        float xv2 = resv[f] + acc2[f];
                        xout[(t0 + f) * BCH + c] = xv2;
                        xs[f * BCH + c] = xv2;
                    }
                }
            }
            __syncthreads();
            if (i < NBLK - 1) {
                stage1_core(tid, lane, wid, t0, nf,
                            w1 + (size_t)(i + 1) * HCH * BCH, p1[i + 1],
                            g1 + (i + 1) * HCH, b1 + (i + 1) * HCH, ynext, redf, statsf, xs);
            } else {
                // ---- mask conv + ReLU + mask encoder + decoder (nf==1 here) ----
                float m = 0.f;
                const float4* wm = (const float4*)(Wmask + c * BCH + p * 32);
                const float4* xv2 = (const float4*)(xs + p * 32);
                #pragma unroll
                for (int j4 = 0; j4 < 8; ++j4) {
                    float4 w = wm[j4]; float4 x = xv2[j4];
                    m += w.x * x.x + w.y * x.y + w.z * x.z + w.w * x.w;
                }
                m += __shfl_xor(m, 1);
                m += __shfl_xor(m, 2);
                if (p == 0)
                    ys[c] = fmaxf(m, 0.f) * outEnc[c * BUF + SHIFT + t0];
                __syncthreads();
                if (tid < 4 * LWIN) {
                    int l = tid >> 2;
                    float e = 0.f;
                    const float4* wd = (const float4*)(Wdec + l * NCH + p * 32);
                    const float4* sv = (const float4*)(ys + p * 32);
                    #pragma unroll
                    for (int j4 = 0; j4 < 8; ++j4) {
                        float4 w = wd[j4]; float4 x = sv[j4];
                        e += w.x * x.x + w.y * x.y + w.z * x.z + w.w * x.w;
                    }
                    e += __shfl_xor(e, 1);
                    e += __shfl_xor(e, 2);
                    if (p == 0) est[t0 * LWIN + l] = e;
                }
            }
        }
        if (i < NBLK - 1) gsync(bar, 2 + i, tid);
        T = Tout;
        const float* tf = xin; xin = xout; xout = (float*)tf;
        const float* ty = ycur; ycur = ynext; ynext = (float*)ty;
    }
}

extern "C" void kernel_launch(void* const* d_in, const int* in_sizes, int n_in,
                              void* d_out, int out_size, void* d_ws, size_t ws_size,
                              hipStream_t stream) {
    const float* mixture = (const float*)d_in[0];
    const float* inEnc   = (const float*)d_in[1];
    const float* inLn    = (const float*)d_in[2];
    const float* Wenc    = (const float*)d_in[3];
    const float* lng     = (const float*)d_in[4];
    const float* lnb     = (const float*)d_in[5];
    const float* Wbn     = (const float*)d_in[6];
    const float* w1      = (const float*)d_in[7];
    const float* p1      = (const float*)d_in[8];
    const float* g1      = (const float*)d_in[9];
    const float* b1      = (const float*)d_in[10];
    const float* dwc     = (const float*)d_in[11];
    const float* p2      = (const float*)d_in[12];
    const float* g2      = (const float*)d_in[13];
    const float* b2      = (const float*)d_in[14];
    const float* w2      = (const float*)d_in[15];
    const float* Wmask   = (const float*)d_in[16];
    const float* Wdec    = (const float*)d_in[17];

    float* est    = (float*)d_out;
    float* outEnc = est + CHUNK;
    float* outLn  = outEnc + NCH * BUF;

    unsigned* bar = (unsigned*)d_ws;       // 32 slots (128 B), zeroed every call
    float* xA   = (float*)d_ws + 32;       // 66048
    float* xB   = xA + BUF * BCH;          // 66048
    float* y1nA = xB + BUF * BCH;          // 264192
    float* y1nB = y1nA + BUF * HCH;        // 264192

    hipMemsetAsync(d_ws, 0, 128, stream);

    void* args[] = { &mixture, &inEnc, &inLn, &Wenc, &lng, &lnb, &Wbn, &w1, &p1,
                     &g1, &b1, &dwc, &p2, &g2, &b2, &w2, &Wmask, &Wdec,
                     &est, &outEnc, &outLn, &bar, &xA, &xB, &y1nA, &y1nB };
    hipLaunchCooperativeKernel((const void*)k_fused, dim3(NWG), dim3(512),
                               (void**)args, 0, stream);
}

// Round 8
// 434.870 us; speedup vs baseline: 4.5885x; 4.5885x over previous
//
#include <hip/hip_runtime.h>

#define CHUNK 400
#define LWIN 50
#define JUMP 8
#define NCH 128
#define BCH 128
#define HCH 512
#define NBLK 14
#define BUF 516
#define SHIFT 508
#define EPSV 1e-8f
#define NWG 136

__device__ __forceinline__ void gsync(unsigned* bar, int slot, int tid) {
    __syncthreads();                       // all WG memory ops drained before signal
    if (tid == 0) {
        unsigned* p = bar + slot;
        __hip_atomic_fetch_add(p, 1u, __ATOMIC_RELEASE, __HIP_MEMORY_SCOPE_AGENT);
        while (__hip_atomic_load(p, __ATOMIC_RELAXED, __HIP_MEMORY_SCOPE_AGENT) < NWG)
            __builtin_amdgcn_s_sleep(4);
        (void)__hip_atomic_load(p, __ATOMIC_ACQUIRE, __HIP_MEMORY_SCOPE_AGENT);
    }
    __syncthreads();
}

// stage1: y1n[t0..t0+nf) = cLN(PReLU(w1 @ xs)); xs is LDS [4][128]
__device__ __forceinline__ void stage1_core(
    int tid, int lane, int wid, int t0, int nf,
    const float* __restrict__ w1b, float aPr,
    const float* __restrict__ gv, const float* __restrict__ bv,
    float* __restrict__ yout, float* redf, float* statsf, const float* xsv)
{
    float acc[4] = {0.f, 0.f, 0.f, 0.f};
    const float4* __restrict__ wr = (const float4*)(w1b + (size_t)tid * BCH);
    const float4* __restrict__ xv = (const float4*)xsv;
    #pragma unroll 4
    for (int c4 = 0; c4 < 32; ++c4) {
        float4 w = wr[c4];
        #pragma unroll
        for (int f = 0; f < 4; ++f) {
            float4 x = xv[f * 32 + c4];
            acc[f] += w.x * x.x + w.y * x.y + w.z * x.z + w.w * x.w;
        }
    }
    #pragma unroll
    for (int f = 0; f < 4; ++f) acc[f] = acc[f] >= 0.f ? acc[f] : aPr * acc[f];
    for (int f = 0; f < nf; ++f) {
        float s = acc[f], q = acc[f] * acc[f];
        #pragma unroll
        for (int o = 32; o; o >>= 1) { s += __shfl_xor(s, o); q += __shfl_xor(q, o); }
        if (lane == 0) { redf[(wid * 4 + f) * 2] = s; redf[(wid * 4 + f) * 2 + 1] = q; }
    }
    __syncthreads();
    if (tid < nf) {
        float s = 0.f, q = 0.f;
        #pragma unroll
        for (int w = 0; w < 8; ++w) { s += redf[(w * 4 + tid) * 2]; q += redf[(w * 4 + tid) * 2 + 1]; }
        float mean = s * (1.f / HCH);
        float var = q * (1.f / HCH) - mean * mean;
        statsf[tid * 2] = mean; statsf[tid * 2 + 1] = rsqrtf(var + EPSV);
    }
    __syncthreads();
    float gg = gv[tid], bb = bv[tid];
    for (int f = 0; f < nf; ++f)
        yout[(t0 + f) * HCH + tid] = gg * (acc[f] - statsf[f * 2]) * statsf[f * 2 + 1] + bb;
}

__global__ __launch_bounds__(512) void k_fused(
    const float* __restrict__ mixture, const float* __restrict__ inEnc,
    const float* __restrict__ inLn, const float* __restrict__ Wenc,
    const float* __restrict__ lng, const float* __restrict__ lnb,
    const float* __restrict__ Wbn, const float* __restrict__ w1,
    const float* __restrict__ p1, const float* __restrict__ g1,
    const float* __restrict__ b1, const float* __restrict__ dwc,
    const float* __restrict__ p2, const float* __restrict__ g2,
    const float* __restrict__ b2, const float* __restrict__ w2,
    const float* __restrict__ Wmask, const float* __restrict__ Wdec,
    float* __restrict__ est, float* __restrict__ outEnc, float* __restrict__ outLn,
    unsigned* __restrict__ bar,
    float* __restrict__ enc, float* __restrict__ xA, float* __restrict__ xB,
    float* __restrict__ y1nA, float* __restrict__ y1nB)
{
    __shared__ float xs[4 * BCH];        // x frames for stage1 / ns for front / sw for dec
    __shared__ float ys[4 * 528];        // stage2 normalized, 132-stride padded groups
    __shared__ float redf[8 * 4 * 2];
    __shared__ float statsf[4 * 2];

    const int wg = blockIdx.x;
    const int tid = threadIdx.x;
    const int lane = tid & 63, wid = tid >> 6;

    // ================= I0: encoder+front (wg<8) | buffer shifts (wg 8..135) =====
    if (wg < 8) {
        int t = wg;
        float e = 0.f;
        if (tid < 128) {
            int c = tid;
            const float* w = Wenc + c * 100;
            const float* m = mixture + t * LWIN;
            #pragma unroll 10
            for (int l = 0; l < LWIN; ++l) e += m[l] * w[l] + m[CHUNK + l] * w[LWIN + l];
            e = fmaxf(e, 0.f);
            enc[c * JUMP + t] = e;
            outEnc[c * BUF + SHIFT + t] = e;
            float s = e, q = e * e;
            #pragma unroll
            for (int o = 32; o; o >>= 1) { s += __shfl_xor(s, o); q += __shfl_xor(q, o); }
            if (lane == 0) { redf[(wid * 4) * 2] = s; redf[(wid * 4) * 2 + 1] = q; }
        }
        __syncthreads();
        if (tid < 128) {
            float S = redf[0] + redf[8], Q = redf[1] + redf[9];
            float mean = S * (1.f / NCH);
            float var = Q * (1.f / NCH) - mean * mean;
            float r = rsqrtf(var + EPSV);
            xs[tid] = lng[tid] * (e - mean) * r + lnb[tid];
        }
        __syncthreads();
        if (tid < 128) {
            float acc = 0.f;
            const float4* wr = (const float4*)(Wbn + tid * NCH);
            const float4* nv = (const float4*)xs;
            #pragma unroll 8
            for (int j4 = 0; j4 < 32; ++j4) {
                float4 w = wr[j4]; float4 x = nv[j4];
                acc += w.x * x.x + w.y * x.y + w.z * x.z + w.w * x.w;
            }
            outLn[tid * BUF + SHIFT + t] = acc;
            xA[(SHIFT + t) * BCH + tid] = acc;
        }
    } else {
        int c = wg - 8;
        if (tid < SHIFT) {
            outEnc[c * BUF + tid] = inEnc[c * BUF + tid + JUMP];
            float v = inLn[c * BUF + tid + JUMP];
            outLn[c * BUF + tid] = v;
            xA[tid * BCH + c] = v;
        }
    }
    gsync(bar, 0, tid);

    // ================= I1: stage1 of block 0 ====================================
    {
        int t0 = 4 * wg;
        if (t0 < BUF) {
            int nf = min(4, BUF - t0);
            for (int idx = tid; idx < nf * BCH; idx += 512) xs[idx] = xA[t0 * BCH + idx];
            __syncthreads();
            stage1_core(tid, lane, wid, t0, nf, w1, p1[0], g1, b1, y1nA, redf, statsf, xs);
        }
    }
    gsync(bar, 1, tid);

    // ================= I2..I15: stage2(i) fused with stage1(i+1) / mask+dec =====
    const float* xin = xA;  float* xout = xB;
    const float* ycur = y1nA; float* ynext = y1nB;
    int T = BUF;
    for (int i = 0; i < NBLK; ++i) {
        int d = 1 << (i % 7);
        int Tout = T - 2 * d;
        int t0 = 4 * wg;
        if (t0 < Tout) {
            int nf = min(4, Tout - t0);
            // ---- depthwise conv + PReLU ----
            const float* dwb = dwc + (size_t)i * HCH * 3;
            float d0 = dwb[tid * 3], d1 = dwb[tid * 3 + 1], d2 = dwb[tid * 3 + 2];
            float a2 = p2[i];
            float y[4];
            for (int f = 0; f < nf; ++f) {
                int t = t0 + f;
                float v = d0 * ycur[t * HCH + tid] + d1 * ycur[(t + d) * HCH + tid]
                        + d2 * ycur[(t + 2 * d) * HCH + tid];
                y[f] = v >= 0.f ? v : a2 * v;
            }
            // ---- cLN over H ----
            for (int f = 0; f < nf; ++f) {
                float s = y[f], q = y[f] * y[f];
                #pragma unroll
                for (int o = 32; o; o >>= 1) { s += __shfl_xor(s, o); q += __shfl_xor(q, o); }
                if (lane == 0) { redf[(wid * 4 + f) * 2] = s; redf[(wid * 4 + f) * 2 + 1] = q; }
            }
            __syncthreads();
            if (tid < nf) {
                float s = 0.f, q = 0.f;
                #pragma unroll
                for (int w = 0; w < 8; ++w) { s += redf[(w * 4 + tid) * 2]; q += redf[(w * 4 + tid) * 2 + 1]; }
                float mean = s * (1.f / HCH);
                float var = q * (1.f / HCH) - mean * mean;
                statsf[tid * 2] = mean; statsf[tid * 2 + 1] = rsqrtf(var + EPSV);
            }
            __syncthreads();
            {
                float gg = g2[i * HCH + tid], bb = b2[i * HCH + tid];
                int pidx = (tid >> 7) * 132 + (tid & 127);
                for (int f = 0; f < nf; ++f)
                    ys[f * 528 + pidx] = gg * (y[f] - statsf[f * 2]) * statsf[f * 2 + 1] + bb;
            }
            __syncthreads();
            // ---- w2 GEMM (K split by 4) + residual ----
            int c = tid >> 2, p = tid & 3;
            float acc[4] = {0.f, 0.f, 0.f, 0.f};
            const float4* wr = (const float4*)(w2 + (size_t)i * BCH * HCH + c * HCH + p * 128);
            const float* yb = ys + p * 132;
            #pragma unroll 4
            for (int j4 = 0; j4 < 32; ++j4) {
                float4 w = wr[j4];
                #pragma unroll
                for (int f = 0; f < 4; ++f) {
                    float4 x = *(const float4*)&yb[f * 528 + j4 * 4];
                    acc[f] += w.x * x.x + w.y * x.y + w.z * x.z + w.w * x.w;
                }
            }
            for (int f = 0; f < nf; ++f) {
                acc[f] += __shfl_xor(acc[f], 1);
                acc[f] += __shfl_xor(acc[f], 2);
            }
            if (p == 0) {
                for (int f = 0; f < nf; ++f) {
                    int t = t0 + f;
                    float xv = xin[(t + 2 * d) * BCH + c] + acc[f];
                    xout[t * BCH + c] = xv;
                    xs[f * BCH + c] = xv;
                }
            }
            __syncthreads();
            // ---- fused next stage1 (or mask+decoder on the last block) ----
            if (i < NBLK - 1) {
                stage1_core(tid, lane, wid, t0, nf,
                            w1 + (size_t)(i + 1) * HCH * BCH, p1[i + 1],
                            g1 + (i + 1) * HCH, b1 + (i + 1) * HCH, ynext, redf, statsf, xs);
            } else {
                int cc = tid & 127, f = tid >> 7;
                float m = 0.f;
                const float4* wm = (const float4*)(Wmask + cc * BCH);
                const float4* xv = (const float4*)(xs + f * BCH);
                #pragma unroll 8
                for (int j4 = 0; j4 < 32; ++j4) {
                    float4 w = wm[j4]; float4 x = xv[j4];
                    m += w.x * x.x + w.y * x.y + w.z * x.z + w.w * x.w;
                }
                m = fmaxf(m, 0.f);
                ys[f * BCH + cc] = m * enc[cc * JUMP + (t0 + f)];
                __syncthreads();
                if (tid < 4 * LWIN) {
                    int ff = tid / LWIN, l = tid % LWIN;
                    float e = 0.f;
                    const float4* wd = (const float4*)(Wdec + l * NCH);
                    const float4* sv = (const float4*)(ys + ff * BCH);
                    #pragma unroll 8
                    for (int j4 = 0; j4 < 32; ++j4) {
                        float4 w = wd[j4]; float4 x = sv[j4];
                        e += w.x * x.x + w.y * x.y + w.z * x.z + w.w * x.w;
                    }
                    est[(t0 + ff) * LWIN + l] = e;
                }
            }
        }
        if (i < NBLK - 1) gsync(bar, 2 + i, tid);
        T = Tout;
        const float* tf = xin; xin = xout; xout = (float*)tf;
        const float* ty = ycur; ycur = ynext; ynext = (float*)ty;
    }
}

extern "C" void kernel_launch(void* const* d_in, const int* in_sizes, int n_in,
                              void* d_out, int out_size, void* d_ws, size_t ws_size,
                              hipStream_t stream) {
    const float* mixture = (const float*)d_in[0];
    const float* inEnc   = (const float*)d_in[1];
    const float* inLn    = (const float*)d_in[2];
    const float* Wenc    = (const float*)d_in[3];
    const float* lng     = (const float*)d_in[4];
    const float* lnb     = (const float*)d_in[5];
    const float* Wbn     = (const float*)d_in[6];
    const float* w1      = (const float*)d_in[7];
    const float* p1      = (const float*)d_in[8];
    const float* g1      = (const float*)d_in[9];
    const float* b1      = (const float*)d_in[10];
    const float* dwc     = (const float*)d_in[11];
    const float* p2      = (const float*)d_in[12];
    const float* g2      = (const float*)d_in[13];
    const float* b2      = (const float*)d_in[14];
    const float* w2      = (const float*)d_in[15];
    const float* Wmask   = (const float*)d_in[16];
    const float* Wdec    = (const float*)d_in[17];

    float* est    = (float*)d_out;
    float* outEnc = est + CHUNK;
    float* outLn  = outEnc + NCH * BUF;

    unsigned* bar = (unsigned*)d_ws;       // 32 slots (128 B), zeroed every call
    float* enc  = (float*)d_ws + 32;       // 1024
    float* xA   = enc + NCH * JUMP;        // 66048
    float* xB   = xA + BUF * BCH;          // 66048
    float* y1nA = xB + BUF * BCH;          // 264192
    float* y1nB = y1nA + BUF * HCH;        // 264192

    hipMemsetAsync(d_ws, 0, 128, stream);

    void* args[] = { &mixture, &inEnc, &inLn, &Wenc, &lng, &lnb, &Wbn, &w1, &p1,
                     &g1, &b1, &dwc, &p2, &g2, &b2, &w2, &Wmask, &Wdec,
                     &est, &outEnc, &outLn, &bar, &enc, &xA, &xB, &y1nA, &y1nB };
    hipLaunchCooperativeKernel((const void*)k_fused, dim3(NWG), dim3(512),
                               (void**)args, 0, stream);
}

// Round 9
// 422.205 us; speedup vs baseline: 4.7262x; 1.0300x over previous
//
#include <hip/hip_runtime.h>

#define CHUNK 400
#define LWIN 50
#define JUMP 8
#define NCH 128
#define BCH 128
#define HCH 512
#define NBLK 14
#define BUF 516
#define SHIFT 508
#define EPSV 1e-8f
#define NWG 136
#define NGRP 8
#define GSIZE 17      // 136 / 8 arrivals per group counter

// two-level tree barrier: 8 spread group counters -> 1 root; ACQ_REL RMW chain
// preserves release-sequence happens-before; waiters poll root only.
__device__ __forceinline__ void gsync(unsigned* bar, int slot, int tid, int wg) {
    __syncthreads();                       // all WG memory ops issued before signal
    if (tid == 0) {
        unsigned* base = bar + slot * (9 * 32);      // 9 counters x 128B apart
        unsigned* loc  = base + (wg & 7) * 32;
        unsigned* root = base + 8 * 32;
        unsigned prev = __hip_atomic_fetch_add(loc, 1u, __ATOMIC_ACQ_REL,
                                               __HIP_MEMORY_SCOPE_AGENT);
        if (prev == GSIZE - 1)             // last arrival of this group
            __hip_atomic_fetch_add(root, 1u, __ATOMIC_ACQ_REL,
                                   __HIP_MEMORY_SCOPE_AGENT);
        while (__hip_atomic_load(root, __ATOMIC_RELAXED, __HIP_MEMORY_SCOPE_AGENT) < NGRP)
            __builtin_amdgcn_s_sleep(2);
        (void)__hip_atomic_load(root, __ATOMIC_ACQUIRE, __HIP_MEMORY_SCOPE_AGENT);
    }
    __syncthreads();
}

// stage1: y1n[t0..t0+nf) = cLN(PReLU(w1 @ xs)); xs is LDS [4][128]
__device__ __forceinline__ void stage1_core(
    int tid, int lane, int wid, int t0, int nf,
    const float* __restrict__ w1b, float aPr,
    const float* __restrict__ gv, const float* __restrict__ bv,
    float* __restrict__ yout, float* redf, float* statsf, const float* xsv)
{
    float acc[4] = {0.f, 0.f, 0.f, 0.f};
    const float4* __restrict__ wr = (const float4*)(w1b + (size_t)tid * BCH);
    const float4* __restrict__ xv = (const float4*)xsv;
    #pragma unroll 4
    for (int c4 = 0; c4 < 32; ++c4) {
        float4 w = wr[c4];
        #pragma unroll
        for (int f = 0; f < 4; ++f) {
            float4 x = xv[f * 32 + c4];
            acc[f] += w.x * x.x + w.y * x.y + w.z * x.z + w.w * x.w;
        }
    }
    #pragma unroll
    for (int f = 0; f < 4; ++f) acc[f] = acc[f] >= 0.f ? acc[f] : aPr * acc[f];
    for (int f = 0; f < nf; ++f) {
        float s = acc[f], q = acc[f] * acc[f];
        #pragma unroll
        for (int o = 32; o; o >>= 1) { s += __shfl_xor(s, o); q += __shfl_xor(q, o); }
        if (lane == 0) { redf[(wid * 4 + f) * 2] = s; redf[(wid * 4 + f) * 2 + 1] = q; }
    }
    __syncthreads();
    if (tid < nf) {
        float s = 0.f, q = 0.f;
        #pragma unroll
        for (int w = 0; w < 8; ++w) { s += redf[(w * 4 + tid) * 2]; q += redf[(w * 4 + tid) * 2 + 1]; }
        float mean = s * (1.f / HCH);
        float var = q * (1.f / HCH) - mean * mean;
        statsf[tid * 2] = mean; statsf[tid * 2 + 1] = rsqrtf(var + EPSV);
    }
    __syncthreads();
    float gg = gv[tid], bb = bv[tid];
    for (int f = 0; f < nf; ++f)
        yout[(t0 + f) * HCH + tid] = gg * (acc[f] - statsf[f * 2]) * statsf[f * 2 + 1] + bb;
}

__global__ __launch_bounds__(512) void k_fused(
    const float* __restrict__ mixture, const float* __restrict__ inEnc,
    const float* __restrict__ inLn, const float* __restrict__ Wenc,
    const float* __restrict__ lng, const float* __restrict__ lnb,
    const float* __restrict__ Wbn, const float* __restrict__ w1,
    const float* __restrict__ p1, const float* __restrict__ g1,
    const float* __restrict__ b1, const float* __restrict__ dwc,
    const float* __restrict__ p2, const float* __restrict__ g2,
    const float* __restrict__ b2, const float* __restrict__ w2,
    const float* __restrict__ Wmask, const float* __restrict__ Wdec,
    float* __restrict__ est, float* __restrict__ outEnc, float* __restrict__ outLn,
    unsigned* __restrict__ bar,
    float* __restrict__ enc, float* __restrict__ xA, float* __restrict__ xB,
    float* __restrict__ y1nA, float* __restrict__ y1nB)
{
    __shared__ float xs[4 * BCH];        // x frames for stage1 / ns for front / sw for dec
    __shared__ float ys[4 * 528];        // stage2 normalized, 132-stride padded groups
    __shared__ float redf[8 * 4 * 2];
    __shared__ float statsf[4 * 2];

    const int wg = blockIdx.x;
    const int tid = threadIdx.x;
    const int lane = tid & 63, wid = tid >> 6;

    // ================= I0: encoder+front (wg<8) | buffer shifts (wg 8..135) =====
    if (wg < 8) {
        int t = wg;
        float e = 0.f;
        if (tid < 128) {
            int c = tid;
            const float* w = Wenc + c * 100;
            const float* m = mixture + t * LWIN;
            #pragma unroll 10
            for (int l = 0; l < LWIN; ++l) e += m[l] * w[l] + m[CHUNK + l] * w[LWIN + l];
            e = fmaxf(e, 0.f);
            enc[c * JUMP + t] = e;
            outEnc[c * BUF + SHIFT + t] = e;
            float s = e, q = e * e;
            #pragma unroll
            for (int o = 32; o; o >>= 1) { s += __shfl_xor(s, o); q += __shfl_xor(q, o); }
            if (lane == 0) { redf[(wid * 4) * 2] = s; redf[(wid * 4) * 2 + 1] = q; }
        }
        __syncthreads();
        if (tid < 128) {
            float S = redf[0] + redf[8], Q = redf[1] + redf[9];
            float mean = S * (1.f / NCH);
            float var = Q * (1.f / NCH) - mean * mean;
            float r = rsqrtf(var + EPSV);
            xs[tid] = lng[tid] * (e - mean) * r + lnb[tid];
        }
        __syncthreads();
        if (tid < 128) {
            float acc = 0.f;
            const float4* wr = (const float4*)(Wbn + tid * NCH);
            const float4* nv = (const float4*)xs;
            #pragma unroll 8
            for (int j4 = 0; j4 < 32; ++j4) {
                float4 w = wr[j4]; float4 x = nv[j4];
                acc += w.x * x.x + w.y * x.y + w.z * x.z + w.w * x.w;
            }
            outLn[tid * BUF + SHIFT + t] = acc;
            xA[(SHIFT + t) * BCH + tid] = acc;
        }
    } else {
        int c = wg - 8;
        if (tid < SHIFT) {
            outEnc[c * BUF + tid] = inEnc[c * BUF + tid + JUMP];
            float v = inLn[c * BUF + tid + JUMP];
            outLn[c * BUF + tid] = v;
            xA[tid * BCH + c] = v;
        }
    }
    gsync(bar, 0, tid, wg);

    // ================= I1: stage1 of block 0 ====================================
    {
        int t0 = 4 * wg;
        if (t0 < BUF) {
            int nf = min(4, BUF - t0);
            for (int idx = tid; idx < nf * BCH; idx += 512) xs[idx] = xA[t0 * BCH + idx];
            __syncthreads();
            stage1_core(tid, lane, wid, t0, nf, w1, p1[0], g1, b1, y1nA, redf, statsf, xs);
        }
    }
    gsync(bar, 1, tid, wg);

    // ================= I2..I15: stage2(i) fused with stage1(i+1) / mask+dec =====
    const float* xin = xA;  float* xout = xB;
    const float* ycur = y1nA; float* ynext = y1nB;
    int T = BUF;
    for (int i = 0; i < NBLK; ++i) {
        int d = 1 << (i % 7);
        int Tout = T - 2 * d;
        int t0 = 4 * wg;
        if (t0 < Tout) {
            int nf = min(4, Tout - t0);
            // ---- depthwise conv + PReLU ----
            const float* dwb = dwc + (size_t)i * HCH * 3;
            float d0 = dwb[tid * 3], d1 = dwb[tid * 3 + 1], d2 = dwb[tid * 3 + 2];
            float a2 = p2[i];
            float y[4];
            for (int f = 0; f < nf; ++f) {
                int t = t0 + f;
                float v = d0 * ycur[t * HCH + tid] + d1 * ycur[(t + d) * HCH + tid]
                        + d2 * ycur[(t + 2 * d) * HCH + tid];
                y[f] = v >= 0.f ? v : a2 * v;
            }
            // ---- cLN over H ----
            for (int f = 0; f < nf; ++f) {
                float s = y[f], q = y[f] * y[f];
                #pragma unroll
                for (int o = 32; o; o >>= 1) { s += __shfl_xor(s, o); q += __shfl_xor(q, o); }
                if (lane == 0) { redf[(wid * 4 + f) * 2] = s; redf[(wid * 4 + f) * 2 + 1] = q; }
            }
            __syncthreads();
            if (tid < nf) {
                float s = 0.f, q = 0.f;
                #pragma unroll
                for (int w = 0; w < 8; ++w) { s += redf[(w * 4 + tid) * 2]; q += redf[(w * 4 + tid) * 2 + 1]; }
                float mean = s * (1.f / HCH);
                float var = q * (1.f / HCH) - mean * mean;
                statsf[tid * 2] = mean; statsf[tid * 2 + 1] = rsqrtf(var + EPSV);
            }
            __syncthreads();
            {
                float gg = g2[i * HCH + tid], bb = b2[i * HCH + tid];
                int pidx = (tid >> 7) * 132 + (tid & 127);
                for (int f = 0; f < nf; ++f)
                    ys[f * 528 + pidx] = gg * (y[f] - statsf[f * 2]) * statsf[f * 2 + 1] + bb;
            }
            __syncthreads();
            // ---- w2 GEMM (K split by 4) + residual ----
            int c = tid >> 2, p = tid & 3;
            float acc[4] = {0.f, 0.f, 0.f, 0.f};
            const float4* wr = (const float4*)(w2 + (size_t)i * BCH * HCH + c * HCH + p * 128);
            const float* yb = ys + p * 132;
            #pragma unroll 4
            for (int j4 = 0; j4 < 32; ++j4) {
                float4 w = wr[j4];
                #pragma unroll
                for (int f = 0; f < 4; ++f) {
                    float4 x = *(const float4*)&yb[f * 528 + j4 * 4];
                    acc[f] += w.x * x.x + w.y * x.y + w.z * x.z + w.w * x.w;
                }
            }
            for (int f = 0; f < nf; ++f) {
                acc[f] += __shfl_xor(acc[f], 1);
                acc[f] += __shfl_xor(acc[f], 2);
            }
            if (p == 0) {
                for (int f = 0; f < nf; ++f) {
                    int t = t0 + f;
                    float xv = xin[(t + 2 * d) * BCH + c] + acc[f];
                    xout[t * BCH + c] = xv;
                    xs[f * BCH + c] = xv;
                }
            }
            __syncthreads();
            // ---- fused next stage1 (or mask+decoder on the last block) ----
            if (i < NBLK - 1) {
                stage1_core(tid, lane, wid, t0, nf,
                            w1 + (size_t)(i + 1) * HCH * BCH, p1[i + 1],
                            g1 + (i + 1) * HCH, b1 + (i + 1) * HCH, ynext, redf, statsf, xs);
            } else {
                int cc = tid & 127, f = tid >> 7;
                float m = 0.f;
                const float4* wm = (const float4*)(Wmask + cc * BCH);
                const float4* xv = (const float4*)(xs + f * BCH);
                #pragma unroll 8
                for (int j4 = 0; j4 < 32; ++j4) {
                    float4 w = wm[j4]; float4 x = xv[j4];
                    m += w.x * x.x + w.y * x.y + w.z * x.z + w.w * x.w;
                }
                m = fmaxf(m, 0.f);
                ys[f * BCH + cc] = m * enc[cc * JUMP + (t0 + f)];
                __syncthreads();
                if (tid < 4 * LWIN) {
                    int ff = tid / LWIN, l = tid % LWIN;
                    float e = 0.f;
                    const float4* wd = (const float4*)(Wdec + l * NCH);
                    const float4* sv = (const float4*)(ys + ff * BCH);
                    #pragma unroll 8
                    for (int j4 = 0; j4 < 32; ++j4) {
                        float4 w = wd[j4]; float4 x = sv[j4];
                        e += w.x * x.x + w.y * x.y + w.z * x.z + w.w * x.w;
                    }
                    est[(t0 + ff) * LWIN + l] = e;
                }
            }
        }
        if (i < NBLK - 1) gsync(bar, 2 + i, tid, wg);
        T = Tout;
        const float* tf = xin; xin = xout; xout = (float*)tf;
        const float* ty = ycur; ycur = ynext; ynext = (float*)ty;
    }
}

extern "C" void kernel_launch(void* const* d_in, const int* in_sizes, int n_in,
                              void* d_out, int out_size, void* d_ws, size_t ws_size,
                              hipStream_t stream) {
    const float* mixture = (const float*)d_in[0];
    const float* inEnc   = (const float*)d_in[1];
    const float* inLn    = (const float*)d_in[2];
    const float* Wenc    = (const float*)d_in[3];
    const float* lng     = (const float*)d_in[4];
    const float* lnb     = (const float*)d_in[5];
    const float* Wbn     = (const float*)d_in[6];
    const float* w1      = (const float*)d_in[7];
    const float* p1      = (const float*)d_in[8];
    const float* g1      = (const float*)d_in[9];
    const float* b1      = (const float*)d_in[10];
    const float* dwc     = (const float*)d_in[11];
    const float* p2      = (const float*)d_in[12];
    const float* g2      = (const float*)d_in[13];
    const float* b2      = (const float*)d_in[14];
    const float* w2      = (const float*)d_in[15];
    const float* Wmask   = (const float*)d_in[16];
    const float* Wdec    = (const float*)d_in[17];

    float* est    = (float*)d_out;
    float* outEnc = est + CHUNK;
    float* outLn  = outEnc + NCH * BUF;

    // barrier: 16 slots x 9 counters x 128B = 18432 B, zeroed every call
    unsigned* bar = (unsigned*)d_ws;
    float* enc  = (float*)d_ws + 4608;     // 1024
    float* xA   = enc + NCH * JUMP;        // 66048
    float* xB   = xA + BUF * BCH;          // 66048
    float* y1nA = xB + BUF * BCH;          // 264192
    float* y1nB = y1nA + BUF * HCH;        // 264192

    hipMemsetAsync(d_ws, 0, 18432, stream);

    void* args[] = { &mixture, &inEnc, &inLn, &Wenc, &lng, &lnb, &Wbn, &w1, &p1,
                     &g1, &b1, &dwc, &p2, &g2, &b2, &w2, &Wmask, &Wdec,
                     &est, &outEnc, &outLn, &bar, &enc, &xA, &xB, &y1nA, &y1nB };
    hipLaunchCooperativeKernel((const void*)k_fused, dim3(NWG), dim3(512),
                               (void**)args, 0, stream);
}

// Round 10
// 410.597 us; speedup vs baseline: 4.8598x; 1.0283x over previous
//
#include <hip/hip_runtime.h>

#define CHUNK 400
#define LWIN 50
#define JUMP 8
#define NCH 128
#define BCH 128
#define HCH 512
#define NBLK 14
#define BUF 516
#define SHIFT 508
#define EPSV 1e-8f
#define NWG 136
#define NGRP 8
#define GSIZE 17      // 136 / 8 arrivals per group counter

// two-level tree barrier. RELEASE RMWs (buffer_wbl2: flush dirty activations to
// L3). doInv=0: no acquire-invalidate -- correctness relies on fresh (never-
// reused) activation buffers + single-writer cache lines for in-kernel reads.
__device__ __forceinline__ void gsync(unsigned* bar, int slot, int tid, int wg, int doInv) {
    __syncthreads();                       // all WG memory ops issued before signal
    if (tid == 0) {
        unsigned* base = bar + slot * (9 * 32);      // 9 counters x 128B apart
        unsigned* loc  = base + (wg & 7) * 32;
        unsigned* root = base + 8 * 32;
        unsigned prev = __hip_atomic_fetch_add(loc, 1u, __ATOMIC_RELEASE,
                                               __HIP_MEMORY_SCOPE_AGENT);
        if (prev == GSIZE - 1)             // last arrival of this group
            __hip_atomic_fetch_add(root, 1u, __ATOMIC_RELEASE,
                                   __HIP_MEMORY_SCOPE_AGENT);
        while (__hip_atomic_load(root, __ATOMIC_RELAXED, __HIP_MEMORY_SCOPE_AGENT) < NGRP)
            __builtin_amdgcn_s_sleep(2);
        if (doInv)
            (void)__hip_atomic_load(root, __ATOMIC_ACQUIRE, __HIP_MEMORY_SCOPE_AGENT);
    }
    __syncthreads();
}

// stage1: y1n[t0..t0+nf) = cLN(PReLU(w1 @ xs)); xs is LDS [4][128]
__device__ __forceinline__ void stage1_core(
    int tid, int lane, int wid, int t0, int nf,
    const float* __restrict__ w1b, float aPr,
    const float* __restrict__ gv, const float* __restrict__ bv,
    float* __restrict__ yout, float* redf, float* statsf, const float* xsv)
{
    float acc[4] = {0.f, 0.f, 0.f, 0.f};
    const float4* __restrict__ wr = (const float4*)(w1b + (size_t)tid * BCH);
    const float4* __restrict__ xv = (const float4*)xsv;
    #pragma unroll 4
    for (int c4 = 0; c4 < 32; ++c4) {
        float4 w = wr[c4];
        #pragma unroll
        for (int f = 0; f < 4; ++f) {
            float4 x = xv[f * 32 + c4];
            acc[f] += w.x * x.x + w.y * x.y + w.z * x.z + w.w * x.w;
        }
    }
    #pragma unroll
    for (int f = 0; f < 4; ++f) acc[f] = acc[f] >= 0.f ? acc[f] : aPr * acc[f];
    for (int f = 0; f < nf; ++f) {
        float s = acc[f], q = acc[f] * acc[f];
        #pragma unroll
        for (int o = 32; o; o >>= 1) { s += __shfl_xor(s, o); q += __shfl_xor(q, o); }
        if (lane == 0) { redf[(wid * 4 + f) * 2] = s; redf[(wid * 4 + f) * 2 + 1] = q; }
    }
    __syncthreads();
    if (tid < nf) {
        float s = 0.f, q = 0.f;
        #pragma unroll
        for (int w = 0; w < 8; ++w) { s += redf[(w * 4 + tid) * 2]; q += redf[(w * 4 + tid) * 2 + 1]; }
        float mean = s * (1.f / HCH);
        float var = q * (1.f / HCH) - mean * mean;
        statsf[tid * 2] = mean; statsf[tid * 2 + 1] = rsqrtf(var + EPSV);
    }
    __syncthreads();
    float gg = gv[tid], bb = bv[tid];
    for (int f = 0; f < nf; ++f)
        yout[(t0 + f) * HCH + tid] = gg * (acc[f] - statsf[f * 2]) * statsf[f * 2 + 1] + bb;
}

__global__ __launch_bounds__(512) void k_fused(
    const float* __restrict__ mixture, const float* __restrict__ inEnc,
    const float* __restrict__ inLn, const float* __restrict__ Wenc,
    const float* __restrict__ lng, const float* __restrict__ lnb,
    const float* __restrict__ Wbn, const float* __restrict__ w1,
    const float* __restrict__ p1, const float* __restrict__ g1,
    const float* __restrict__ b1, const float* __restrict__ dwc,
    const float* __restrict__ p2, const float* __restrict__ g2,
    const float* __restrict__ b2, const float* __restrict__ w2,
    const float* __restrict__ Wmask, const float* __restrict__ Wdec,
    float* __restrict__ est, float* __restrict__ outEnc, float* __restrict__ outLn,
    unsigned* __restrict__ bar, float* __restrict__ enc,
    float* __restrict__ xbuf, float* __restrict__ ybuf,
    int nx, int ny, int doInv)
{
    __shared__ float xs[4 * BCH];        // x frames for stage1 / ns for front / sw for dec
    __shared__ float ys[4 * 528];        // stage2 normalized, 132-stride padded groups
    __shared__ float redf[8 * 4 * 2];
    __shared__ float statsf[4 * 2];

    const int wg = blockIdx.x;
    const int tid = threadIdx.x;
    const int lane = tid & 63, wid = tid >> 6;

    // ===== I0: encoder+front (wg<8) | frame-major copies (wg 8..135) =========
    if (wg < 8) {
        int t = wg;
        float e = 0.f;
        if (tid < 128) {
            int c = tid;
            const float* w = Wenc + c * 100;
            const float* m = mixture + t * LWIN;
            #pragma unroll 10
            for (int l = 0; l < LWIN; ++l) e += m[l] * w[l] + m[CHUNK + l] * w[LWIN + l];
            e = fmaxf(e, 0.f);
            enc[t * NCH + c] = e;               // [t][c]: single-writer lines
            outEnc[c * BUF + SHIFT + t] = e;    // write-only output
            float s = e, q = e * e;
            #pragma unroll
            for (int o = 32; o; o >>= 1) { s += __shfl_xor(s, o); q += __shfl_xor(q, o); }
            if (lane == 0) { redf[(wid * 4) * 2] = s; redf[(wid * 4) * 2 + 1] = q; }
        }
        __syncthreads();
        if (tid < 128) {
            float S = redf[0] + redf[8], Q = redf[1] + redf[9];
            float mean = S * (1.f / NCH);
            float var = Q * (1.f / NCH) - mean * mean;
            float r = rsqrtf(var + EPSV);
            xs[tid] = lng[tid] * (e - mean) * r + lnb[tid];
        }
        __syncthreads();
        if (tid < 128) {
            float acc = 0.f;
            const float4* wr = (const float4*)(Wbn + tid * NCH);
            const float4* nv = (const float4*)xs;
            #pragma unroll 8
            for (int j4 = 0; j4 < 32; ++j4) {
                float4 w = wr[j4]; float4 x = nv[j4];
                acc += w.x * x.x + w.y * x.y + w.z * x.z + w.w * x.w;
            }
            outLn[tid * BUF + SHIFT + t] = acc;
            xbuf[(SHIFT + t) * BCH + tid] = acc;   // x0 tail: full frame line
        }
    } else {
        int ch = wg - 8;                           // 0..127
        for (int t = tid; t < SHIFT; t += 512)     // outEnc row ch (write-only)
            outEnc[ch * BUF + t] = inEnc[ch * BUF + t + JUMP];
        if (ch < 127) {                            // frames 4ch..4ch+3 of x0 (frame-major)
            int f = tid >> 7, c = tid & 127;
            int t = 4 * ch + f;
            float v = inLn[c * BUF + t + JUMP];
            xbuf[t * BCH + c] = v;                 // single-writer frame lines
            outLn[c * BUF + t] = v;                // write-only output
        }
    }
    gsync(bar, 0, tid, wg, doInv);

    // ===== I1: stage1 of block 0 =============================================
    {
        int t0 = 4 * wg;
        if (t0 < BUF) {
            int nf = min(4, BUF - t0);
            for (int idx = tid; idx < nf * BCH; idx += 512) xs[idx] = xbuf[t0 * BCH + idx];
            __syncthreads();
            stage1_core(tid, lane, wid, t0, nf, w1, p1[0], g1, b1, ybuf, redf, statsf, xs);
        }
    }
    gsync(bar, 1, tid, wg, doInv);

    // ===== I2..I15: stage2(i) fused with stage1(i+1) / mask+dec ==============
    const float* xin = xbuf;
    int T = BUF;
    for (int i = 0; i < NBLK; ++i) {
        float* xout = xbuf + (size_t)((i + 1) % nx) * (BUF * BCH);
        const float* ycur = ybuf + (size_t)(i % ny) * (BUF * HCH);
        float* ynext = ybuf + (size_t)((i + 1) % ny) * (BUF * HCH);
        int d = 1 << (i % 7);
        int Tout = T - 2 * d;
        int t0 = 4 * wg;
        if (t0 < Tout) {
            int nf = min(4, Tout - t0);
            // ---- depthwise conv + PReLU ----
            const float* dwb = dwc + (size_t)i * HCH * 3;
            float d0 = dwb[tid * 3], d1 = dwb[tid * 3 + 1], d2 = dwb[tid * 3 + 2];
            float a2 = p2[i];
            float y[4];
            for (int f = 0; f < nf; ++f) {
                int t = t0 + f;
                float v = d0 * ycur[t * HCH + tid] + d1 * ycur[(t + d) * HCH + tid]
                        + d2 * ycur[(t + 2 * d) * HCH + tid];
                y[f] = v >= 0.f ? v : a2 * v;
            }
            // ---- cLN over H ----
            for (int f = 0; f < nf; ++f) {
                float s = y[f], q = y[f] * y[f];
                #pragma unroll
                for (int o = 32; o; o >>= 1) { s += __shfl_xor(s, o); q += __shfl_xor(q, o); }
                if (lane == 0) { redf[(wid * 4 + f) * 2] = s; redf[(wid * 4 + f) * 2 + 1] = q; }
            }
            __syncthreads();
            if (tid < nf) {
                float s = 0.f, q = 0.f;
                #pragma unroll
                for (int w = 0; w < 8; ++w) { s += redf[(w * 4 + tid) * 2]; q += redf[(w * 4 + tid) * 2 + 1]; }
                float mean = s * (1.f / HCH);
                float var = q * (1.f / HCH) - mean * mean;
                statsf[tid * 2] = mean; statsf[tid * 2 + 1] = rsqrtf(var + EPSV);
            }
            __syncthreads();
            {
                float gg = g2[i * HCH + tid], bb = b2[i * HCH + tid];
                int pidx = (tid >> 7) * 132 + (tid & 127);
                for (int f = 0; f < nf; ++f)
                    ys[f * 528 + pidx] = gg * (y[f] - statsf[f * 2]) * statsf[f * 2 + 1] + bb;
            }
            __syncthreads();
            // ---- w2 GEMM (K split by 4) + residual ----
            int c = tid >> 2, p = tid & 3;
            float acc[4] = {0.f, 0.f, 0.f, 0.f};
            const float4* wr = (const float4*)(w2 + (size_t)i * BCH * HCH + c * HCH + p * 128);
            const float* yb = ys + p * 132;
            #pragma unroll 4
            for (int j4 = 0; j4 < 32; ++j4) {
                float4 w = wr[j4];
                #pragma unroll
                for (int f = 0; f < 4; ++f) {
                    float4 x = *(const float4*)&yb[f * 528 + j4 * 4];
                    acc[f] += w.x * x.x + w.y * x.y + w.z * x.z + w.w * x.w;
                }
            }
            for (int f = 0; f < nf; ++f) {
                acc[f] += __shfl_xor(acc[f], 1);
                acc[f] += __shfl_xor(acc[f], 2);
            }
            if (p == 0) {
                for (int f = 0; f < nf; ++f) {
                    int t = t0 + f;
                    float xv = xin[(t + 2 * d) * BCH + c] + acc[f];
                    xout[t * BCH + c] = xv;
                    xs[f * BCH + c] = xv;
                }
            }
            __syncthreads();
            // ---- fused next stage1 (or mask+decoder on the last block) ----
            if (i < NBLK - 1) {
                stage1_core(tid, lane, wid, t0, nf,
                            w1 + (size_t)(i + 1) * HCH * BCH, p1[i + 1],
                            g1 + (i + 1) * HCH, b1 + (i + 1) * HCH, ynext, redf, statsf, xs);
            } else {
                int cc = tid & 127, f = tid >> 7;
                float m = 0.f;
                const float4* wm = (const float4*)(Wmask + cc * BCH);
                const float4* xv = (const float4*)(xs + f * BCH);
                #pragma unroll 8
                for (int j4 = 0; j4 < 32; ++j4) {
                    float4 w = wm[j4]; float4 x = xv[j4];
                    m += w.x * x.x + w.y * x.y + w.z * x.z + w.w * x.w;
                }
                m = fmaxf(m, 0.f);
                ys[f * BCH + cc] = m * enc[(t0 + f) * NCH + cc];
                __syncthreads();
                if (tid < 4 * LWIN) {
                    int ff = tid / LWIN, l = tid % LWIN;
                    float e = 0.f;
                    const float4* wd = (const float4*)(Wdec + l * NCH);
                    const float4* sv = (const float4*)(ys + ff * BCH);
                    #pragma unroll 8
                    for (int j4 = 0; j4 < 32; ++j4) {
                        float4 w = wd[j4]; float4 x = sv[j4];
                        e += w.x * x.x + w.y * x.y + w.z * x.z + w.w * x.w;
                    }
                    est[(t0 + ff) * LWIN + l] = e;
                }
            }
        }
        if (i < NBLK - 1) gsync(bar, 2 + i, tid, wg, doInv);
        T = Tout;
        xin = xout;
    }
}

extern "C" void kernel_launch(void* const* d_in, const int* in_sizes, int n_in,
                              void* d_out, int out_size, void* d_ws, size_t ws_size,
                              hipStream_t stream) {
    const float* mixture = (const float*)d_in[0];
    const float* inEnc   = (const float*)d_in[1];
    const float* inLn    = (const float*)d_in[2];
    const float* Wenc    = (const float*)d_in[3];
    const float* lng     = (const float*)d_in[4];
    const float* lnb     = (const float*)d_in[5];
    const float* Wbn     = (const float*)d_in[6];
    const float* w1      = (const float*)d_in[7];
    const float* p1      = (const float*)d_in[8];
    const float* g1      = (const float*)d_in[9];
    const float* b1      = (const float*)d_in[10];
    const float* dwc     = (const float*)d_in[11];
    const float* p2      = (const float*)d_in[12];
    const float* g2      = (const float*)d_in[13];
    const float* b2      = (const float*)d_in[14];
    const float* w2      = (const float*)d_in[15];
    const float* Wmask   = (const float*)d_in[16];
    const float* Wdec    = (const float*)d_in[17];

    float* est    = (float*)d_out;
    float* outEnc = est + CHUNK;
    float* outLn  = outEnc + NCH * BUF;

    unsigned* bar = (unsigned*)d_ws;          // 16 slots x 9 x 128B = 18432 B
    float* enc  = (float*)d_ws + 4608;        // 1024 floats, [t][c]
    float* xbuf = enc + 1024;
    const size_t xstr = (size_t)BUF * BCH;    // 66048
    const size_t ystr = (size_t)BUF * HCH;    // 264192
    const size_t head = 4608 + 1024;

    int nx, ny, doInv;
    size_t need_fresh = (head + 15 * xstr + 14 * ystr) * 4ull;  // ~18.8 MB
    if (ws_size >= need_fresh) { nx = 15; ny = 14; doInv = 0; } // fresh buffers, no L2 inv
    else                       { nx = 2;  ny = 2;  doInv = 1; } // ping-pong + acquire-inv
    float* ybuf = xbuf + (size_t)nx * xstr;

    hipMemsetAsync(d_ws, 0, 18432, stream);

    void* args[] = { &mixture, &inEnc, &inLn, &Wenc, &lng, &lnb, &Wbn, &w1, &p1,
                     &g1, &b1, &dwc, &p2, &g2, &b2, &w2, &Wmask, &Wdec,
                     &est, &outEnc, &outLn, &bar, &enc, &xbuf, &ybuf,
                     &nx, &ny, &doInv };
    hipLaunchCooperativeKernel((const void*)k_fused, dim3(NWG), dim3(512),
                               (void**)args, 0, stream);
}

// Round 11
// 389.317 us; speedup vs baseline: 5.1254x; 1.0547x over previous
//
#include <hip/hip_runtime.h>

#define CHUNK 400
#define LWIN 50
#define JUMP 8
#define NCH 128
#define BCH 128
#define HCH 512
#define NBLK 14
#define BUF 516
#define SHIFT 508
#define EPSV 1e-8f
#define NWG 136
#define NGRP 8
#define GSIZE 17      // 136 / 8 arrivals per group counter

// agent-coherent scalar store: handled at the coherence point (bypasses the
// non-coherent per-XCD L2), so NO buffer_wbl2 release walk is needed anywhere.
__device__ __forceinline__ void cstore(float* p, float v) {
    __hip_atomic_store(p, v, __ATOMIC_RELAXED, __HIP_MEMORY_SCOPE_AGENT);
}

// two-level tree barrier, ALL RELAXED (no release-wbl2, no acquire-inv).
// Ordering: __syncthreads() drains vmcnt (coherent stores acked at L3) before
// tid0's arrival RMW; data addresses are launch-fresh so consumer L2 is clean.
// doInv=1 (buffer-reuse fallback) adds the acquire-invalidate back.
__device__ __forceinline__ void gsync(unsigned* bar, int slot, int tid, int wg, int doInv) {
    __syncthreads();
    if (tid == 0) {
        unsigned* base = bar + slot * (9 * 32);      // 9 counters x 128B apart
        unsigned* loc  = base + (wg & 7) * 32;
        unsigned* root = base + 8 * 32;
        unsigned prev = __hip_atomic_fetch_add(loc, 1u, __ATOMIC_RELAXED,
                                               __HIP_MEMORY_SCOPE_AGENT);
        if (prev == GSIZE - 1)             // last arrival of this group
            __hip_atomic_fetch_add(root, 1u, __ATOMIC_RELAXED,
                                   __HIP_MEMORY_SCOPE_AGENT);
        while (__hip_atomic_load(root, __ATOMIC_RELAXED, __HIP_MEMORY_SCOPE_AGENT) < NGRP)
            __builtin_amdgcn_s_sleep(2);
        if (doInv)
            (void)__hip_atomic_load(root, __ATOMIC_ACQUIRE, __HIP_MEMORY_SCOPE_AGENT);
    }
    __syncthreads();
}

// stage1: y1n[t0..t0+nf) = cLN(PReLU(w1 @ xs)); xs is LDS [4][128]
__device__ __forceinline__ void stage1_core(
    int tid, int lane, int wid, int t0, int nf,
    const float* __restrict__ w1b, float aPr,
    const float* __restrict__ gv, const float* __restrict__ bv,
    float* __restrict__ yout, float* redf, float* statsf, const float* xsv)
{
    float acc[4] = {0.f, 0.f, 0.f, 0.f};
    const float4* __restrict__ wr = (const float4*)(w1b + (size_t)tid * BCH);
    const float4* __restrict__ xv = (const float4*)xsv;
    #pragma unroll 4
    for (int c4 = 0; c4 < 32; ++c4) {
        float4 w = wr[c4];
        #pragma unroll
        for (int f = 0; f < 4; ++f) {
            float4 x = xv[f * 32 + c4];
            acc[f] += w.x * x.x + w.y * x.y + w.z * x.z + w.w * x.w;
        }
    }
    #pragma unroll
    for (int f = 0; f < 4; ++f) acc[f] = acc[f] >= 0.f ? acc[f] : aPr * acc[f];
    for (int f = 0; f < nf; ++f) {
        float s = acc[f], q = acc[f] * acc[f];
        #pragma unroll
        for (int o = 32; o; o >>= 1) { s += __shfl_xor(s, o); q += __shfl_xor(q, o); }
        if (lane == 0) { redf[(wid * 4 + f) * 2] = s; redf[(wid * 4 + f) * 2 + 1] = q; }
    }
    __syncthreads();
    if (tid < nf) {
        float s = 0.f, q = 0.f;
        #pragma unroll
        for (int w = 0; w < 8; ++w) { s += redf[(w * 4 + tid) * 2]; q += redf[(w * 4 + tid) * 2 + 1]; }
        float mean = s * (1.f / HCH);
        float var = q * (1.f / HCH) - mean * mean;
        statsf[tid * 2] = mean; statsf[tid * 2 + 1] = rsqrtf(var + EPSV);
    }
    __syncthreads();
    float gg = gv[tid], bb = bv[tid];
    for (int f = 0; f < nf; ++f)
        cstore(&yout[(t0 + f) * HCH + tid],
               gg * (acc[f] - statsf[f * 2]) * statsf[f * 2 + 1] + bb);
}

__global__ __launch_bounds__(512) void k_fused(
    const float* __restrict__ mixture, const float* __restrict__ inEnc,
    const float* __restrict__ inLn, const float* __restrict__ Wenc,
    const float* __restrict__ lng, const float* __restrict__ lnb,
    const float* __restrict__ Wbn, const float* __restrict__ w1,
    const float* __restrict__ p1, const float* __restrict__ g1,
    const float* __restrict__ b1, const float* __restrict__ dwc,
    const float* __restrict__ p2, const float* __restrict__ g2,
    const float* __restrict__ b2, const float* __restrict__ w2,
    const float* __restrict__ Wmask, const float* __restrict__ Wdec,
    float* __restrict__ est, float* __restrict__ outEnc, float* __restrict__ outLn,
    unsigned* __restrict__ bar, float* __restrict__ enc,
    float* __restrict__ xbuf, float* __restrict__ ybuf,
    int nx, int ny, int doInv)
{
    __shared__ float xs[4 * BCH];        // x frames for stage1 / ns for front / sw for dec
    __shared__ float ys[4 * 528];        // stage2 normalized, 132-stride padded groups
    __shared__ float redf[8 * 4 * 2];
    __shared__ float statsf[4 * 2];

    const int wg = blockIdx.x;
    const int tid = threadIdx.x;
    const int lane = tid & 63, wid = tid >> 6;

    // ===== I0: encoder+front (wg<8) | frame-major copies (wg 8..135) =========
    if (wg < 8) {
        int t = wg;
        float e = 0.f;
        if (tid < 128) {
            int c = tid;
            const float* w = Wenc + c * 100;
            const float* m = mixture + t * LWIN;
            #pragma unroll 10
            for (int l = 0; l < LWIN; ++l) e += m[l] * w[l] + m[CHUNK + l] * w[LWIN + l];
            e = fmaxf(e, 0.f);
            cstore(&enc[t * NCH + c], e);       // read by other WGs in final phase
            outEnc[c * BUF + SHIFT + t] = e;    // write-only output
            float s = e, q = e * e;
            #pragma unroll
            for (int o = 32; o; o >>= 1) { s += __shfl_xor(s, o); q += __shfl_xor(q, o); }
            if (lane == 0) { redf[(wid * 4) * 2] = s; redf[(wid * 4) * 2 + 1] = q; }
        }
        __syncthreads();
        if (tid < 128) {
            float S = redf[0] + redf[8], Q = redf[1] + redf[9];
            float mean = S * (1.f / NCH);
            float var = Q * (1.f / NCH) - mean * mean;
            float r = rsqrtf(var + EPSV);
            xs[tid] = lng[tid] * (e - mean) * r + lnb[tid];
        }
        __syncthreads();
        if (tid < 128) {
            float acc = 0.f;
            const float4* wr = (const float4*)(Wbn + tid * NCH);
            const float4* nv = (const float4*)xs;
            #pragma unroll 8
            for (int j4 = 0; j4 < 32; ++j4) {
                float4 w = wr[j4]; float4 x = nv[j4];
                acc += w.x * x.x + w.y * x.y + w.z * x.z + w.w * x.w;
            }
            outLn[tid * BUF + SHIFT + t] = acc;
            cstore(&xbuf[(SHIFT + t) * BCH + tid], acc);
        }
    } else {
        int ch = wg - 8;                           // 0..127
        for (int t = tid; t < SHIFT; t += 512)     // outEnc row ch (write-only)
            outEnc[ch * BUF + t] = inEnc[ch * BUF + t + JUMP];
        if (ch < 127) {                            // frames 4ch..4ch+3 of x0
            int f = tid >> 7, c = tid & 127;
            int t = 4 * ch + f;
            float v = inLn[c * BUF + t + JUMP];
            cstore(&xbuf[t * BCH + c], v);
            outLn[c * BUF + t] = v;                // write-only output
        }
    }
    gsync(bar, 0, tid, wg, doInv);

    // ===== I1: stage1 of block 0 =============================================
    {
        int t0 = 4 * wg;
        if (t0 < BUF) {
            int nf = min(4, BUF - t0);
            for (int idx = tid; idx < nf * BCH; idx += 512) xs[idx] = xbuf[t0 * BCH + idx];
            __syncthreads();
            stage1_core(tid, lane, wid, t0, nf, w1, p1[0], g1, b1, ybuf, redf, statsf, xs);
        }
    }
    gsync(bar, 1, tid, wg, doInv);

    // ===== I2..I15: stage2(i) fused with stage1(i+1) / mask+dec ==============
    const float* xin = xbuf;
    int T = BUF;
    for (int i = 0; i < NBLK; ++i) {
        float* xout = xbuf + (size_t)((i + 1) % nx) * (BUF * BCH);
        const float* ycur = ybuf + (size_t)(i % ny) * (BUF * HCH);
        float* ynext = ybuf + (size_t)((i + 1) % ny) * (BUF * HCH);
        int d = 1 << (i % 7);
        int Tout = T - 2 * d;
        int t0 = 4 * wg;
        if (t0 < Tout) {
            int nf = min(4, Tout - t0);
            // ---- depthwise conv + PReLU ----
            const float* dwb = dwc + (size_t)i * HCH * 3;
            float d0 = dwb[tid * 3], d1 = dwb[tid * 3 + 1], d2 = dwb[tid * 3 + 2];
            float a2 = p2[i];
            float y[4];
            for (int f = 0; f < nf; ++f) {
                int t = t0 + f;
                float v = d0 * ycur[t * HCH + tid] + d1 * ycur[(t + d) * HCH + tid]
                        + d2 * ycur[(t + 2 * d) * HCH + tid];
                y[f] = v >= 0.f ? v : a2 * v;
            }
            // ---- cLN over H ----
            for (int f = 0; f < nf; ++f) {
                float s = y[f], q = y[f] * y[f];
                #pragma unroll
                for (int o = 32; o; o >>= 1) { s += __shfl_xor(s, o); q += __shfl_xor(q, o); }
                if (lane == 0) { redf[(wid * 4 + f) * 2] = s; redf[(wid * 4 + f) * 2 + 1] = q; }
            }
            __syncthreads();
            if (tid < nf) {
                float s = 0.f, q = 0.f;
                #pragma unroll
                for (int w = 0; w < 8; ++w) { s += redf[(w * 4 + tid) * 2]; q += redf[(w * 4 + tid) * 2 + 1]; }
                float mean = s * (1.f / HCH);
                float var = q * (1.f / HCH) - mean * mean;
                statsf[tid * 2] = mean; statsf[tid * 2 + 1] = rsqrtf(var + EPSV);
            }
            __syncthreads();
            {
                float gg = g2[i * HCH + tid], bb = b2[i * HCH + tid];
                int pidx = (tid >> 7) * 132 + (tid & 127);
                for (int f = 0; f < nf; ++f)
                    ys[f * 528 + pidx] = gg * (y[f] - statsf[f * 2]) * statsf[f * 2 + 1] + bb;
            }
            __syncthreads();
            // ---- w2 GEMM (K split by 4) + residual ----
            int c = tid >> 2, p = tid & 3;
            float acc[4] = {0.f, 0.f, 0.f, 0.f};
            const float4* wr = (const float4*)(w2 + (size_t)i * BCH * HCH + c * HCH + p * 128);
            const float* yb = ys + p * 132;
            #pragma unroll 4
            for (int j4 = 0; j4 < 32; ++j4) {
                float4 w = wr[j4];
                #pragma unroll
                for (int f = 0; f < 4; ++f) {
                    float4 x = *(const float4*)&yb[f * 528 + j4 * 4];
                    acc[f] += w.x * x.x + w.y * x.y + w.z * x.z + w.w * x.w;
                }
            }
            for (int f = 0; f < nf; ++f) {
                acc[f] += __shfl_xor(acc[f], 1);
                acc[f] += __shfl_xor(acc[f], 2);
            }
            if (p == 0) {
                for (int f = 0; f < nf; ++f) {
                    int t = t0 + f;
                    float xv = xin[(t + 2 * d) * BCH + c] + acc[f];
                    cstore(&xout[t * BCH + c], xv);
                    xs[f * BCH + c] = xv;
                }
            }
            __syncthreads();
            // ---- fused next stage1 (or mask+decoder on the last block) ----
            if (i < NBLK - 1) {
                stage1_core(tid, lane, wid, t0, nf,
                            w1 + (size_t)(i + 1) * HCH * BCH, p1[i + 1],
                            g1 + (i + 1) * HCH, b1 + (i + 1) * HCH, ynext, redf, statsf, xs);
            } else {
                int cc = tid & 127, f = tid >> 7;
                float m = 0.f;
                const float4* wm = (const float4*)(Wmask + cc * BCH);
                const float4* xv = (const float4*)(xs + f * BCH);
                #pragma unroll 8
                for (int j4 = 0; j4 < 32; ++j4) {
                    float4 w = wm[j4]; float4 x = xv[j4];
                    m += w.x * x.x + w.y * x.y + w.z * x.z + w.w * x.w;
                }
                m = fmaxf(m, 0.f);
                ys[f * BCH + cc] = m * enc[(t0 + f) * NCH + cc];
                __syncthreads();
                if (tid < 4 * LWIN) {
                    int ff = tid / LWIN, l = tid % LWIN;
                    float e = 0.f;
                    const float4* wd = (const float4*)(Wdec + l * NCH);
                    const float4* sv = (const float4*)(ys + ff * BCH);
                    #pragma unroll 8
                    for (int j4 = 0; j4 < 32; ++j4) {
                        float4 w = wd[j4]; float4 x = sv[j4];
                        e += w.x * x.x + w.y * x.y + w.z * x.z + w.w * x.w;
                    }
                    est[(t0 + ff) * LWIN + l] = e;
                }
            }
        }
        if (i < NBLK - 1) gsync(bar, 2 + i, tid, wg, doInv);
        T = Tout;
        xin = xout;
    }
}

extern "C" void kernel_launch(void* const* d_in, const int* in_sizes, int n_in,
                              void* d_out, int out_size, void* d_ws, size_t ws_size,
                              hipStream_t stream) {
    const float* mixture = (const float*)d_in[0];
    const float* inEnc   = (const float*)d_in[1];
    const float* inLn    = (const float*)d_in[2];
    const float* Wenc    = (const float*)d_in[3];
    const float* lng     = (const float*)d_in[4];
    const float* lnb     = (const float*)d_in[5];
    const float* Wbn     = (const float*)d_in[6];
    const float* w1      = (const float*)d_in[7];
    const float* p1      = (const float*)d_in[8];
    const float* g1      = (const float*)d_in[9];
    const float* b1      = (const float*)d_in[10];
    const float* dwc     = (const float*)d_in[11];
    const float* p2      = (const float*)d_in[12];
    const float* g2      = (const float*)d_in[13];
    const float* b2      = (const float*)d_in[14];
    const float* w2      = (const float*)d_in[15];
    const float* Wmask   = (const float*)d_in[16];
    const float* Wdec    = (const float*)d_in[17];

    float* est    = (float*)d_out;
    float* outEnc = est + CHUNK;
    float* outLn  = outEnc + NCH * BUF;

    unsigned* bar = (unsigned*)d_ws;          // 16 slots x 9 x 128B = 18432 B
    float* enc  = (float*)d_ws + 4608;        // 1024 floats, [t][c]
    float* xbuf = enc + 1024;
    const size_t xstr = (size_t)BUF * BCH;    // 66048
    const size_t ystr = (size_t)BUF * HCH;    // 264192
    const size_t head = 4608 + 1024;

    int nx, ny, doInv;
    size_t need_fresh = (head + 15 * xstr + 14 * ystr) * 4ull;  // ~18.8 MB
    if (ws_size >= need_fresh) { nx = 15; ny = 14; doInv = 0; } // fresh buffers
    else                       { nx = 2;  ny = 2;  doInv = 1; } // reuse + acquire-inv
    float* ybuf = xbuf + (size_t)nx * xstr;

    hipMemsetAsync(d_ws, 0, 18432, stream);

    void* args[] = { &mixture, &inEnc, &inLn, &Wenc, &lng, &lnb, &Wbn, &w1, &p1,
                     &g1, &b1, &dwc, &p2, &g2, &b2, &w2, &Wmask, &Wdec,
                     &est, &outEnc, &outLn, &bar, &enc, &xbuf, &ybuf,
                     &nx, &ny, &doInv };
    hipLaunchCooperativeKernel((const void*)k_fused, dim3(NWG), dim3(512),
                               (void**)args, 0, stream);
}

// Round 12
// 377.829 us; speedup vs baseline: 5.2812x; 1.0304x over previous
//
#include <hip/hip_runtime.h>

#define CHUNK 400
#define LWIN 50
#define JUMP 8
#define NCH 128
#define BCH 128
#define HCH 512
#define NBLK 14
#define BUF 516
#define SHIFT 508
#define EPSV 1e-8f
#define NWG 136
#define NGRP 8
#define GSIZE 17

// agent-coherent store: lands at the coherence point (bypasses per-XCD L2)
__device__ __forceinline__ void cstore(float* p, float v) {
    __hip_atomic_store(p, v, __ATOMIC_RELAXED, __HIP_MEMORY_SCOPE_AGENT);
}

// ---- mode 1 (fallback, buffer reuse): R11 tree barrier ----
__device__ __forceinline__ void gsync(unsigned* bar, int slot, int tid, int wg) {
    __syncthreads();
    if (tid == 0) {
        unsigned* base = bar + slot * (9 * 32);
        unsigned* loc  = base + (wg & 7) * 32;
        unsigned* root = base + 8 * 32;
        unsigned prev = __hip_atomic_fetch_add(loc, 1u, __ATOMIC_RELAXED,
                                               __HIP_MEMORY_SCOPE_AGENT);
        if (prev == GSIZE - 1)
            __hip_atomic_fetch_add(root, 1u, __ATOMIC_RELAXED,
                                   __HIP_MEMORY_SCOPE_AGENT);
        while (__hip_atomic_load(root, __ATOMIC_RELAXED, __HIP_MEMORY_SCOPE_AGENT) < NGRP)
            __builtin_amdgcn_s_sleep(2);
        (void)__hip_atomic_load(root, __ATOMIC_ACQUIRE, __HIP_MEMORY_SCOPE_AGENT);
    }
    __syncthreads();
}

// ---- mode 0 (fresh buffers): point-to-point tile flags ----
// parallel-poll cnt flags starting at flp[base]; lanes 0..cnt-1 each own one.
__device__ __forceinline__ void fwait(unsigned* flp, int base, int cnt, int tid) {
    if (tid < cnt) {
        unsigned* p = flp + base + tid;
        while (__hip_atomic_load(p, __ATOMIC_RELAXED, __HIP_MEMORY_SCOPE_AGENT) == 0)
            __builtin_amdgcn_s_sleep(1);
    }
    __syncthreads();                   // join + order data loads after flag obs
}
// __syncthreads drains each wave's vmcnt (cstores acked at L3) before publish
__device__ __forceinline__ void fset(unsigned* flp, int idx, int tid) {
    __syncthreads();
    if (tid == 0)
        __hip_atomic_store(flp + idx, 1u, __ATOMIC_RELAXED, __HIP_MEMORY_SCOPE_AGENT);
}

// stage1: y1n[t0..t0+nf) = cLN(PReLU(w1 @ xs)); xs is LDS [4][128]
__device__ __forceinline__ void stage1_core(
    int tid, int lane, int wid, int t0, int nf,
    const float* __restrict__ w1b, float aPr,
    const float* __restrict__ gv, const float* __restrict__ bv,
    float* __restrict__ yout, float* redf, float* statsf, const float* xsv)
{
    float acc[4] = {0.f, 0.f, 0.f, 0.f};
    const float4* __restrict__ wr = (const float4*)(w1b + (size_t)tid * BCH);
    const float4* __restrict__ xv = (const float4*)xsv;
    #pragma unroll 4
    for (int c4 = 0; c4 < 32; ++c4) {
        float4 w = wr[c4];
        #pragma unroll
        for (int f = 0; f < 4; ++f) {
            float4 x = xv[f * 32 + c4];
            acc[f] += w.x * x.x + w.y * x.y + w.z * x.z + w.w * x.w;
        }
    }
    #pragma unroll
    for (int f = 0; f < 4; ++f) acc[f] = acc[f] >= 0.f ? acc[f] : aPr * acc[f];
    for (int f = 0; f < nf; ++f) {
        float s = acc[f], q = acc[f] * acc[f];
        #pragma unroll
        for (int o = 32; o; o >>= 1) { s += __shfl_xor(s, o); q += __shfl_xor(q, o); }
        if (lane == 0) { redf[(wid * 4 + f) * 2] = s; redf[(wid * 4 + f) * 2 + 1] = q; }
    }
    __syncthreads();
    if (tid < nf) {
        float s = 0.f, q = 0.f;
        #pragma unroll
        for (int w = 0; w < 8; ++w) { s += redf[(w * 4 + tid) * 2]; q += redf[(w * 4 + tid) * 2 + 1]; }
        float mean = s * (1.f / HCH);
        float var = q * (1.f / HCH) - mean * mean;
        statsf[tid * 2] = mean; statsf[tid * 2 + 1] = rsqrtf(var + EPSV);
    }
    __syncthreads();
    float gg = gv[tid], bb = bv[tid];
    for (int f = 0; f < nf; ++f)
        cstore(&yout[(t0 + f) * HCH + tid],
               gg * (acc[f] - statsf[f * 2]) * statsf[f * 2 + 1] + bb);
}

__global__ __launch_bounds__(512) void k_fused(
    const float* __restrict__ mixture, const float* __restrict__ inEnc,
    const float* __restrict__ inLn, const float* __restrict__ Wenc,
    const float* __restrict__ lng, const float* __restrict__ lnb,
    const float* __restrict__ Wbn, const float* __restrict__ w1,
    const float* __restrict__ p1, const float* __restrict__ g1,
    const float* __restrict__ b1, const float* __restrict__ dwc,
    const float* __restrict__ p2, const float* __restrict__ g2,
    const float* __restrict__ b2, const float* __restrict__ w2,
    const float* __restrict__ Wmask, const float* __restrict__ Wdec,
    float* __restrict__ est, float* __restrict__ outEnc, float* __restrict__ outLn,
    unsigned* __restrict__ fl, float* __restrict__ enc,
    float* __restrict__ xbuf, float* __restrict__ ybuf,
    int nx, int ny, int mode)
{
    __shared__ float xs[4 * BCH];
    __shared__ float ys[4 * 528];
    __shared__ float redf[8 * 4 * 2];
    __shared__ float statsf[4 * 2];

    const int wg = blockIdx.x;
    const int tid = threadIdx.x;
    const int lane = tid & 63, wid = tid >> 6;
    const int j = wg;

    // ===== phase 0: encoder+front (wg<8) | frame-major copies (wg 8..135) ====
    if (wg < 8) {
        int t = wg;
        float e = 0.f;
        if (tid < 128) {
            int c = tid;
            const float* w = Wenc + c * 100;
            const float* m = mixture + t * LWIN;
            #pragma unroll 10
            for (int l = 0; l < LWIN; ++l) e += m[l] * w[l] + m[CHUNK + l] * w[LWIN + l];
            e = fmaxf(e, 0.f);
            cstore(&enc[t * NCH + c], e);
            outEnc[c * BUF + SHIFT + t] = e;
            float s = e, q = e * e;
            #pragma unroll
            for (int o = 32; o; o >>= 1) { s += __shfl_xor(s, o); q += __shfl_xor(q, o); }
            if (lane == 0) { redf[(wid * 4) * 2] = s; redf[(wid * 4) * 2 + 1] = q; }
        }
        __syncthreads();
        if (tid < 128) {
            float S = redf[0] + redf[8], Q = redf[1] + redf[9];
            float mean = S * (1.f / NCH);
            float var = Q * (1.f / NCH) - mean * mean;
            float r = rsqrtf(var + EPSV);
            xs[tid] = lng[tid] * (e - mean) * r + lnb[tid];
        }
        __syncthreads();
        if (tid < 128) {
            float acc = 0.f;
            const float4* wr = (const float4*)(Wbn + tid * NCH);
            const float4* nv = (const float4*)xs;
            #pragma unroll 8
            for (int j4 = 0; j4 < 32; ++j4) {
                float4 w = wr[j4]; float4 x = nv[j4];
                acc += w.x * x.x + w.y * x.y + w.z * x.z + w.w * x.w;
            }
            outLn[tid * BUF + SHIFT + t] = acc;
            cstore(&xbuf[(SHIFT + t) * BCH + tid], acc);
        }
    } else {
        int ch = wg - 8;                           // 0..127
        for (int t = tid; t < SHIFT; t += 512)
            outEnc[ch * BUF + t] = inEnc[ch * BUF + t + JUMP];
        if (ch < 127) {                            // frames 4ch..4ch+3 of x0
            int f = tid >> 7, c = tid & 127;
            int t = 4 * ch + f;
            float v = inLn[c * BUF + t + JUMP];
            cstore(&xbuf[t * BCH + c], v);
            outLn[c * BUF + t] = v;
        }
    }
    if (mode == 0) fset(fl, 0 * NWG + wg, tid); else gsync(fl, 0, tid, wg);

    // ===== phase 1: stage1 of block 0 ========================================
    if (4 * j < BUF) {
        if (mode == 0) {
            int base, cnt;                 // x0 tile j producers (phase 0)
            if (j <= 126)      { base = 8 + j; cnt = 1; }
            else if (j == 127) { base = 0;     cnt = 4; }   // frames 508-511 <- wg 0-3
            else               { base = 4;     cnt = 4; }   // frames 512-515 <- wg 4-7
            fwait(fl, base, cnt, tid);
        }
        int t0 = 4 * j;
        int nf = min(4, BUF - t0);
        for (int idx = tid; idx < nf * BCH; idx += 512) xs[idx] = xbuf[t0 * BCH + idx];
        __syncthreads();
        stage1_core(tid, lane, wid, t0, nf, w1, p1[0], g1, b1, ybuf, redf, statsf, xs);
    }
    if (mode == 0) fset(fl, 1 * NWG + wg, tid); else gsync(fl, 1, tid, wg);

    // ===== phases 2..15: stage2(i) fused with stage1(i+1) / mask+dec =========
    const float* xin = xbuf;
    int T = BUF;
    for (int i = 0; i < NBLK; ++i) {
        float* xout = xbuf + (size_t)((i + 1) % nx) * (BUF * BCH);
        const float* ycur = ybuf + (size_t)(i % ny) * (BUF * HCH);
        float* ynext = ybuf + (size_t)((i + 1) % ny) * (BUF * HCH);
        int d = 1 << (i % 7);
        int Tout = T - 2 * d;
        int t0 = 4 * j;
        if (t0 < Tout) {
            if (mode == 0) {               // wait only on the tiles we read
                int jmaxe = (T - 1) >> 2;
                int jmax = min(j + ((3 + 2 * d) >> 2), jmaxe);
                fwait(fl + (1 + i) * NWG, j, jmax - j + 1, tid);
                if (i == NBLK - 1) fwait(fl, 4 * j, 4, tid);  // enc frames 4j..4j+3
            }
            int nf = min(4, Tout - t0);
            // ---- depthwise conv + PReLU ----
            const float* dwb = dwc + (size_t)i * HCH * 3;
            float d0 = dwb[tid * 3], d1 = dwb[tid * 3 + 1], d2 = dwb[tid * 3 + 2];
            float a2 = p2[i];
            float y[4];
            for (int f = 0; f < nf; ++f) {
                int t = t0 + f;
                float v = d0 * ycur[t * HCH + tid] + d1 * ycur[(t + d) * HCH + tid]
                        + d2 * ycur[(t + 2 * d) * HCH + tid];
                y[f] = v >= 0.f ? v : a2 * v;
            }
            // ---- cLN over H ----
            for (int f = 0; f < nf; ++f) {
                float s = y[f], q = y[f] * y[f];
                #pragma unroll
                for (int o = 32; o; o >>= 1) { s += __shfl_xor(s, o); q += __shfl_xor(q, o); }
                if (lane == 0) { redf[(wid * 4 + f) * 2] = s; redf[(wid * 4 + f) * 2 + 1] = q; }
            }
            __syncthreads();
            if (tid < nf) {
                float s = 0.f, q = 0.f;
                #pragma unroll
                for (int w = 0; w < 8; ++w) { s += redf[(w * 4 + tid) * 2]; q += redf[(w * 4 + tid) * 2 + 1]; }
                float mean = s * (1.f / HCH);
                float var = q * (1.f / HCH) - mean * mean;
                statsf[tid * 2] = mean; statsf[tid * 2 + 1] = rsqrtf(var + EPSV);
            }
            __syncthreads();
            {
                float gg = g2[i * HCH + tid], bb = b2[i * HCH + tid];
                int pidx = (tid >> 7) * 132 + (tid & 127);
                for (int f = 0; f < nf; ++f)
                    ys[f * 528 + pidx] = gg * (y[f] - statsf[f * 2]) * statsf[f * 2 + 1] + bb;
            }
            __syncthreads();
            // ---- w2 GEMM (K split by 4) + residual ----
            int c = tid >> 2, p = tid & 3;
            float acc[4] = {0.f, 0.f, 0.f, 0.f};
            const float4* wr = (const float4*)(w2 + (size_t)i * BCH * HCH + c * HCH + p * 128);
            const float* yb = ys + p * 132;
            #pragma unroll 4
            for (int j4 = 0; j4 < 32; ++j4) {
                float4 w = wr[j4];
                #pragma unroll
                for (int f = 0; f < 4; ++f) {
                    float4 x = *(const float4*)&yb[f * 528 + j4 * 4];
                    acc[f] += w.x * x.x + w.y * x.y + w.z * x.z + w.w * x.w;
                }
            }
            for (int f = 0; f < nf; ++f) {
                acc[f] += __shfl_xor(acc[f], 1);
                acc[f] += __shfl_xor(acc[f], 2);
            }
            if (p == 0) {
                for (int f = 0; f < nf; ++f) {
                    int t = t0 + f;
                    float xv = xin[(t + 2 * d) * BCH + c] + acc[f];
                    cstore(&xout[t * BCH + c], xv);
                    xs[f * BCH + c] = xv;
                }
            }
            __syncthreads();
            // ---- fused next stage1 (or mask+decoder on the last block) ----
            if (i < NBLK - 1) {
                stage1_core(tid, lane, wid, t0, nf,
                            w1 + (size_t)(i + 1) * HCH * BCH, p1[i + 1],
                            g1 + (i + 1) * HCH, b1 + (i + 1) * HCH, ynext, redf, statsf, xs);
            } else {
                int cc = tid & 127, f = tid >> 7;
                float m = 0.f;
                const float4* wm = (const float4*)(Wmask + cc * BCH);
                const float4* xv = (const float4*)(xs + f * BCH);
                #pragma unroll 8
                for (int j4 = 0; j4 < 32; ++j4) {
                    float4 w = wm[j4]; float4 x = xv[j4];
                    m += w.x * x.x + w.y * x.y + w.z * x.z + w.w * x.w;
                }
                m = fmaxf(m, 0.f);
                ys[f * BCH + cc] = m * enc[(t0 + f) * NCH + cc];
                __syncthreads();
                if (tid < 4 * LWIN) {
                    int ff = tid / LWIN, l = tid % LWIN;
                    float e = 0.f;
                    const float4* wd = (const float4*)(Wdec + l * NCH);
                    const float4* sv = (const float4*)(ys + ff * BCH);
                    #pragma unroll 8
                    for (int j4 = 0; j4 < 32; ++j4) {
                        float4 w = wd[j4]; float4 x = sv[j4];
                        e += w.x * x.x + w.y * x.y + w.z * x.z + w.w * x.w;
                    }
                    est[(t0 + ff) * LWIN + l] = e;
                }
            }
        }
        if (mode == 0) fset(fl, (2 + i) * NWG + wg, tid);
        else if (i < NBLK - 1) gsync(fl, 2 + i, tid, wg);
        T = Tout;
        xin = xout;
    }
}

extern "C" void kernel_launch(void* const* d_in, const int* in_sizes, int n_in,
                              void* d_out, int out_size, void* d_ws, size_t ws_size,
                              hipStream_t stream) {
    const float* mixture = (const float*)d_in[0];
    const float* inEnc   = (const float*)d_in[1];
    const float* inLn    = (const float*)d_in[2];
    const float* Wenc    = (const float*)d_in[3];
    const float* lng     = (const float*)d_in[4];
    const float* lnb     = (const float*)d_in[5];
    const float* Wbn     = (const float*)d_in[6];
    const float* w1      = (const float*)d_in[7];
    const float* p1      = (const float*)d_in[8];
    const float* g1      = (const float*)d_in[9];
    const float* b1      = (const float*)d_in[10];
    const float* dwc     = (const float*)d_in[11];
    const float* p2      = (const float*)d_in[12];
    const float* g2      = (const float*)d_in[13];
    const float* b2      = (const float*)d_in[14];
    const float* w2      = (const float*)d_in[15];
    const float* Wmask   = (const float*)d_in[16];
    const float* Wdec    = (const float*)d_in[17];

    float* est    = (float*)d_out;
    float* outEnc = est + CHUNK;
    float* outLn  = outEnc + NCH * BUF;

    unsigned* fl = (unsigned*)d_ws;           // mode0: 16x136 flags; mode1: tree (18432 B)
    float* enc  = (float*)d_ws + 4608;        // after 18432 B
    float* xbuf = enc + 1024;
    const size_t xstr = (size_t)BUF * BCH;    // 66048
    const size_t ystr = (size_t)BUF * HCH;    // 264192

    int nx, ny, mode;
    size_t need_fresh = (4608 + 1024 + 15 * xstr + 14 * ystr) * 4ull;  // ~18.8 MB
    if (ws_size >= need_fresh) { nx = 15; ny = 14; mode = 0; }  // fresh buffers + flags
    else                       { nx = 2;  ny = 2;  mode = 1; }  // reuse + tree barrier
    float* ybuf = xbuf + (size_t)nx * xstr;

    hipMemsetAsync(d_ws, 0, 18432, stream);

    void* args[] = { &mixture, &inEnc, &inLn, &Wenc, &lng, &lnb, &Wbn, &w1, &p1,
                     &g1, &b1, &dwc, &p2, &g2, &b2, &w2, &Wmask, &Wdec,
                     &est, &outEnc, &outLn, &fl, &enc, &xbuf, &ybuf,
                     &nx, &ny, &mode };
    hipLaunchCooperativeKernel((const void*)k_fused, dim3(NWG), dim3(512),
                               (void**)args, 0, stream);
}